// Round 12
// baseline (135.653 us; speedup 1.0000x reference)
//
#include <hip/hip_runtime.h>

// FoveatedSamplingConv2d — bf16 MFMA implicit GEMM, 4-px-per-lane gathers,
// 3-STAGE register pipeline (covers ~300cyc L2 latency), NT output stores,
// XCD-aligned prep (xs rows written on the XCD that reads them).
// 4 shifted replicate-padded bf16 copies make every tap gather 8B-aligned.

#define HH 256
#define WW 256
#define INC 3
#define OC 64
#define KS 11
#define BB 4
#define NKC 12           // K chunks of 32 (3*128/32)
#define PH 326           // 256 + 2*35
#define PW 512           // padded row stride
#define PAD 35
#define NPAR 4           // shifted copies
#define HALFR 163        // PH/2 rows per XCD half

typedef __attribute__((ext_vector_type(4))) float f32x4;
typedef __attribute__((ext_vector_type(8))) short s16x8;
typedef unsigned int u32;
typedef unsigned short u16;

static __device__ __forceinline__ u16 f2bf(float f) {
    u32 u = __builtin_bit_cast(u32, f);
    u32 r = (u + 0x7FFFu + ((u >> 16) & 1u)) >> 16;   // RTNE (finite data)
    return (u16)r;
}

// ---- fused prep -----------------------------------------------------------
// blocks [0,96): W fragments. blocks [96,96+7824): pad copies, XCD-aligned:
//   target XCD k = pb&7 = 2*b + (py>=163) — matches main's reader mapping.
__global__ void __launch_bounds__(256)
prep_fused(const float* __restrict__ x, const float* __restrict__ w,
           u16* __restrict__ xs, u16* __restrict__ wf) {
    const int tid = threadIdx.x;
    if (blockIdx.x < 96) {
        int i = blockIdx.x * 256 + tid;              // 0..24575
        int j    = i & 7;
        int lane = (i >> 3) & 63;
        int ot   = (i >> 9) & 3;
        int kc   = i >> 11;
        int o  = ot * 16 + (lane & 15);
        int k  = kc * 32 + ((lane >> 4) << 3) + j;
        int c  = k >> 7;
        int tt = k & 127;
        float val = 0.f;
        if (tt < 121) {
            int ky = tt / 11, kx = tt % 11;
            val = w[((o * INC + c) * KS + ky) * KS + kx];
        }
        wf[i] = f2bf(val);
    } else {
        const int pb = blockIdx.x - 96;              // 0..7823
        const int k  = pb & 7;                       // target XCD
        const int i  = pb >> 3;                      // 0..977
        const int r  = i * 2 + (tid >> 7);           // 0..1955
        const int zl = r / HALFR;                    // 0..11  (par,c) plane
        const int pz = r - zl * HALFR;               // 0..162
        const int b    = k >> 1;
        const int py   = (k & 1) * HALFR + pz;       // 0..325
        const int c    = zl % INC;
        const int par  = zl / INC;                   // 0..3
        const int z    = (b * NPAR + par) * INC + c;
        const int px0  = (tid & 127) * 4;
        const int sy   = min(max(py - PAD, 0), HH - 1);
        const float* src = x + (((size_t)b * INC + c) * HH + sy) * WW;
        ushort4 o4;
        int s0 = min(max(px0 + 0 - PAD + par, 0), WW - 1);
        int s1 = min(max(px0 + 1 - PAD + par, 0), WW - 1);
        int s2 = min(max(px0 + 2 - PAD + par, 0), WW - 1);
        int s3 = min(max(px0 + 3 - PAD + par, 0), WW - 1);
        o4.x = f2bf(src[s0]); o4.y = f2bf(src[s1]);
        o4.z = f2bf(src[s2]); o4.w = f2bf(src[s3]);
        *(ushort4*)&xs[((size_t)z * PH + py) * PW + px0] = o4;
    }
}

// ---- main: 4 waves; wave = 64 px (4 MFMA tiles); 3-stage kc pipeline -----
__global__ void __launch_bounds__(256, 4)
fov_mfma5(const u16* __restrict__ xs, const u16* __restrict__ wf,
          const float* __restrict__ bias, float* __restrict__ out) {
    __shared__ u32 offF[NKC * 32];
    const int tid = threadIdx.x;
    for (int t = tid; t < NKC * 32; t += 256) {
        int c = t >> 7, tt = t & 127;
        int dy = 0, dx = 0;
        if (tt < 121) {
            int ky = tt / 11, kx = tt - (tt / 11) * 11;
            int ay = ky - 5, ax = kx - 5;
            int d = max(abs(ay), abs(ax));
            int sc = (d <= 1) ? 1 : (d == 2 ? 3 : (d == 3 ? 5 : 7));
            dy = ay * sc; dx = ax * sc;
        }
        int par = (PAD + dx) & 3;
        offF[t] = (u32)(((((par * INC + c) * PH) + (PAD + dy)) * PW
                         + (PAD + dx - par)) * 2);
    }
    __syncthreads();

    const int lane = tid & 63;
    const int wv   = tid >> 6;
    // bijective XCD swizzle: XCD = bid&7 = 2*b + (h>=128)
    const int obid = (blockIdx.x & 7) * 128 + (blockIdx.x >> 3);
    const int b = obid >> 8;
    const int h = obid & 255;
    const int g16 = lane & 15;         // pixel group: px = wv*64 + 4*g16 + T
    const int kg  = lane >> 4;         // tap group within chunk

    const char* xpb = (const char*)(xs + (size_t)b * (NPAR * INC * PH * PW));
    const u32 pxoff = (u32)((h * PW + wv * 64 + 4 * g16) * 2);
    const s16x8* wbase = (const s16x8*)wf;

    f32x4 acc[4][4];                   // [tile T][o-block]
#pragma unroll
    for (int T = 0; T < 4; ++T)
#pragma unroll
        for (int ob = 0; ob < 4; ++ob) acc[T][ob] = (f32x4){0, 0, 0, 0};

    uint2 G[3][8];                     // gather TRIPLE buffer
    s16x8 A[2][4];                     // weight double buffer

#define STAGE_G(S, KC)                                                    \
    {                                                                     \
        const uint4* fp = (const uint4*)&offF[(KC) * 32 + kg * 8];        \
        const uint4 fA = fp[0], fB = fp[1];                               \
        G[S][0] = *(const uint2*)(xpb + (pxoff + fA.x));                  \
        G[S][1] = *(const uint2*)(xpb + (pxoff + fA.y));                  \
        G[S][2] = *(const uint2*)(xpb + (pxoff + fA.z));                  \
        G[S][3] = *(const uint2*)(xpb + (pxoff + fA.w));                  \
        G[S][4] = *(const uint2*)(xpb + (pxoff + fB.x));                  \
        G[S][5] = *(const uint2*)(xpb + (pxoff + fB.y));                  \
        G[S][6] = *(const uint2*)(xpb + (pxoff + fB.z));                  \
        G[S][7] = *(const uint2*)(xpb + (pxoff + fB.w));                  \
    }

    // prologue: stage kc = 0, 1 (gathers) and kc = 0 (weights)
    STAGE_G(0, 0)
    STAGE_G(1, 1)
    {
        const s16x8* wp = wbase + lane;
        A[0][0] = wp[0]; A[0][1] = wp[64]; A[0][2] = wp[128]; A[0][3] = wp[192];
    }

#pragma unroll
    for (int kc = 0; kc < NKC; ++kc) {
        const int cur = kc % 3;
        const int pre = (kc + 2) % 3;
        if (kc + 2 < NKC) STAGE_G(pre, kc + 2)        // prefetch 2 ahead
        if (kc + 1 < NKC) {                           // weights 1 ahead
            const s16x8* wp = wbase + (((kc + 1) << 8) + lane);
            A[(kc + 1) & 1][0] = wp[0];   A[(kc + 1) & 1][1] = wp[64];
            A[(kc + 1) & 1][2] = wp[128]; A[(kc + 1) & 1][3] = wp[192];
        }
        __builtin_amdgcn_s_setprio(1);
#pragma unroll
        for (int T = 0; T < 4; ++T) {
            const u32 sel = (T & 1) ? 0x07060302u : 0x05040100u;
            const bool hi = (T >> 1) != 0;
            union { u32 u[4]; s16x8 v; } bu;
            bu.u[0] = __builtin_amdgcn_perm(hi ? G[cur][1].y : G[cur][1].x,
                                            hi ? G[cur][0].y : G[cur][0].x, sel);
            bu.u[1] = __builtin_amdgcn_perm(hi ? G[cur][3].y : G[cur][3].x,
                                            hi ? G[cur][2].y : G[cur][2].x, sel);
            bu.u[2] = __builtin_amdgcn_perm(hi ? G[cur][5].y : G[cur][5].x,
                                            hi ? G[cur][4].y : G[cur][4].x, sel);
            bu.u[3] = __builtin_amdgcn_perm(hi ? G[cur][7].y : G[cur][7].x,
                                            hi ? G[cur][6].y : G[cur][6].x, sel);

            acc[T][0] = __builtin_amdgcn_mfma_f32_16x16x32_bf16(A[kc & 1][0], bu.v, acc[T][0], 0, 0, 0);
            acc[T][1] = __builtin_amdgcn_mfma_f32_16x16x32_bf16(A[kc & 1][1], bu.v, acc[T][1], 0, 0, 0);
            acc[T][2] = __builtin_amdgcn_mfma_f32_16x16x32_bf16(A[kc & 1][2], bu.v, acc[T][2], 0, 0, 0);
            acc[T][3] = __builtin_amdgcn_mfma_f32_16x16x32_bf16(A[kc & 1][3], bu.v, acc[T][3], 0, 0, 0);
        }
        __builtin_amdgcn_s_setprio(0);
    }
#undef STAGE_G

    // D: col = lane&15 = pixel-group; row = kg*4 + r = o within 16-block.
    const int orow = kg << 2;
    const float4* bp = (const float4*)bias;
#pragma unroll
    for (int ob = 0; ob < 4; ++ob) {
        const float4 bb = bp[ob * 4 + kg];
        const float bv[4] = {bb.x, bb.y, bb.z, bb.w};
#pragma unroll
        for (int r = 0; r < 4; ++r) {
            const int o = ob * 16 + orow + r;
            f32x4 st;
            st[0] = acc[0][ob][r] + bv[r];
            st[1] = acc[1][ob][r] + bv[r];
            st[2] = acc[2][ob][r] + bv[r];
            st[3] = acc[3][ob][r] + bv[r];
            float* op = out + (((size_t)b * OC + o) * HH + h) * WW + wv * 64 + 4 * g16;
            __builtin_nontemporal_store(st, (f32x4*)op);
        }
    }
}

// ================= fallback (R1 fp32 path, tiny ws) ======================
__global__ void fovconv_transpose_w(const float* __restrict__ w,
                                    float* __restrict__ wT) {
    int i = blockIdx.x * 256 + threadIdx.x;
    const int N = OC * INC * KS * KS;
    if (i < N) {
        int o  = i / (INC * KS * KS);
        int ct = i % (INC * KS * KS);
        wT[ct * OC + o] = w[i];
    }
}

__global__ void __launch_bounds__(256)
fovconv_main(const float* __restrict__ x, const float* __restrict__ wT,
             const float* __restrict__ bias, float* __restrict__ out) {
    const int wpix = threadIdx.x;
    const int h    = blockIdx.x & (HH - 1);
    const int b    = blockIdx.x >> 8;
    float acc[OC];
#pragma unroll
    for (int o = 0; o < OC; ++o) acc[o] = 0.f;
    const float* xbp = x + (size_t)b * INC * HH * WW;
    for (int k = 0; k < KS; ++k) {
        const int dy = k - 5;
        for (int l = 0; l < KS; ++l) {
            const int dx = l - 5;
            const int d  = max(abs(dy), abs(dx));
            const int scale = (d <= 1) ? 1 : (d == 2 ? 3 : (d == 3 ? 5 : 7));
            const int sy = min(max(h + dy * scale, 0), HH - 1);
            const int sx = min(max(wpix + dx * scale, 0), WW - 1);
            const int base = sy * WW + sx;
            const int t = k * KS + l;
#pragma unroll
            for (int c = 0; c < INC; ++c) {
                const float xv = xbp[c * (HH * WW) + base];
                const float* wp = wT + (c * (KS * KS) + t) * OC;
#pragma unroll
                for (int o = 0; o < OC; ++o)
                    acc[o] = fmaf(xv, wp[o], acc[o]);
            }
        }
    }
    float* op = out + (((size_t)b * OC) * HH + h) * WW + wpix;
#pragma unroll
    for (int o = 0; o < OC; ++o)
        op[(size_t)o * HH * WW] = acc[o] + bias[o];
}

extern "C" void kernel_launch(void* const* d_in, const int* in_sizes, int n_in,
                              void* d_out, int out_size, void* d_ws, size_t ws_size,
                              hipStream_t stream) {
    const float* x    = (const float*)d_in[0];
    const float* wgt  = (const float*)d_in[1];
    const float* bias = (const float*)d_in[2];
    float* out = (float*)d_out;

    const size_t xs_bytes = (size_t)BB * NPAR * INC * PH * PW * 2;  // 16,023,552
    const size_t wf_bytes = (size_t)NKC * 4 * 64 * 8 * 2;           //     49,152

    if (ws_size >= xs_bytes + wf_bytes) {
        u16* xsb = (u16*)d_ws;
        u16* wf  = (u16*)((char*)d_ws + xs_bytes);
        prep_fused<<<96 + 978 * 8, 256, 0, stream>>>(x, wgt, xsb, wf);
        fov_mfma5<<<BB * HH, 256, 0, stream>>>(xsb, wf, bias, out);
    } else {
        float* wT = (float*)d_ws;
        const int NW = OC * INC * KS * KS;
        fovconv_transpose_w<<<(NW + 255) / 256, 256, 0, stream>>>(wgt, wT);
        fovconv_main<<<BB * HH, 256, 0, stream>>>(x, wT, bias, out);
    }
}

// Round 13
// 36.647 us; speedup vs baseline: 3.7016x; 3.7016x over previous
//
#include <hip/hip_runtime.h>

// FoveatedSamplingConv2d — bf16 MFMA implicit GEMM, 4-px-per-lane gathers,
// 3-stage register pipeline at 3 blocks/CU (NO spill: 64 AGPR acc + ~84 VGPR
// fits the 170 cap), NT output stores, XCD-aligned prep.
// 4 shifted replicate-padded bf16 copies make every tap gather 8B-aligned.

#define HH 256
#define WW 256
#define INC 3
#define OC 64
#define KS 11
#define BB 4
#define NKC 12           // K chunks of 32 (3*128/32)
#define PH 326           // 256 + 2*35
#define PW 512           // padded row stride
#define PAD 35
#define NPAR 4           // shifted copies
#define HALFR 163        // PH/2 rows per XCD half

typedef __attribute__((ext_vector_type(4))) float f32x4;
typedef __attribute__((ext_vector_type(8))) short s16x8;
typedef unsigned int u32;
typedef unsigned short u16;

static __device__ __forceinline__ u16 f2bf(float f) {
    u32 u = __builtin_bit_cast(u32, f);
    u32 r = (u + 0x7FFFu + ((u >> 16) & 1u)) >> 16;   // RTNE (finite data)
    return (u16)r;
}

// ---- fused prep -----------------------------------------------------------
// blocks [0,96): W fragments. blocks [96,96+7824): pad copies, XCD-aligned:
//   target XCD k = pb&7 = 2*b + (py>=163) — matches main's reader mapping.
__global__ void __launch_bounds__(256)
prep_fused(const float* __restrict__ x, const float* __restrict__ w,
           u16* __restrict__ xs, u16* __restrict__ wf) {
    const int tid = threadIdx.x;
    if (blockIdx.x < 96) {
        int i = blockIdx.x * 256 + tid;              // 0..24575
        int j    = i & 7;
        int lane = (i >> 3) & 63;
        int ot   = (i >> 9) & 3;
        int kc   = i >> 11;
        int o  = ot * 16 + (lane & 15);
        int k  = kc * 32 + ((lane >> 4) << 3) + j;
        int c  = k >> 7;
        int tt = k & 127;
        float val = 0.f;
        if (tt < 121) {
            int ky = tt / 11, kx = tt % 11;
            val = w[((o * INC + c) * KS + ky) * KS + kx];
        }
        wf[i] = f2bf(val);
    } else {
        const int pb = blockIdx.x - 96;              // 0..7823
        const int k  = pb & 7;                       // target XCD
        const int i  = pb >> 3;                      // 0..977
        const int r  = i * 2 + (tid >> 7);           // 0..1955
        const int zl = r / HALFR;                    // 0..11  (par,c) plane
        const int pz = r - zl * HALFR;               // 0..162
        const int b    = k >> 1;
        const int py   = (k & 1) * HALFR + pz;       // 0..325
        const int c    = zl % INC;
        const int par  = zl / INC;                   // 0..3
        const int z    = (b * NPAR + par) * INC + c;
        const int px0  = (tid & 127) * 4;
        const int sy   = min(max(py - PAD, 0), HH - 1);
        const float* src = x + (((size_t)b * INC + c) * HH + sy) * WW;
        ushort4 o4;
        int s0 = min(max(px0 + 0 - PAD + par, 0), WW - 1);
        int s1 = min(max(px0 + 1 - PAD + par, 0), WW - 1);
        int s2 = min(max(px0 + 2 - PAD + par, 0), WW - 1);
        int s3 = min(max(px0 + 3 - PAD + par, 0), WW - 1);
        o4.x = f2bf(src[s0]); o4.y = f2bf(src[s1]);
        o4.z = f2bf(src[s2]); o4.w = f2bf(src[s3]);
        *(ushort4*)&xs[((size_t)z * PH + py) * PW + px0] = o4;
    }
}

// ---- main: 4 waves; wave = 64 px (4 MFMA tiles); 3-stage kc pipeline -----
__global__ void __launch_bounds__(256, 3)
fov_mfma5(const u16* __restrict__ xs, const u16* __restrict__ wf,
          const float* __restrict__ bias, float* __restrict__ out) {
    __shared__ u32 offF[NKC * 32];
    const int tid = threadIdx.x;
    for (int t = tid; t < NKC * 32; t += 256) {
        int c = t >> 7, tt = t & 127;
        int dy = 0, dx = 0;
        if (tt < 121) {
            int ky = tt / 11, kx = tt - (tt / 11) * 11;
            int ay = ky - 5, ax = kx - 5;
            int d = max(abs(ay), abs(ax));
            int sc = (d <= 1) ? 1 : (d == 2 ? 3 : (d == 3 ? 5 : 7));
            dy = ay * sc; dx = ax * sc;
        }
        int par = (PAD + dx) & 3;
        offF[t] = (u32)(((((par * INC + c) * PH) + (PAD + dy)) * PW
                         + (PAD + dx - par)) * 2);
    }
    __syncthreads();

    const int lane = tid & 63;
    const int wv   = tid >> 6;
    // bijective XCD swizzle: XCD = bid&7 = 2*b + (h>=128)
    const int obid = (blockIdx.x & 7) * 128 + (blockIdx.x >> 3);
    const int b = obid >> 8;
    const int h = obid & 255;
    const int g16 = lane & 15;         // pixel group: px = wv*64 + 4*g16 + T
    const int kg  = lane >> 4;         // tap group within chunk

    const char* xpb = (const char*)(xs + (size_t)b * (NPAR * INC * PH * PW));
    const u32 pxoff = (u32)((h * PW + wv * 64 + 4 * g16) * 2);
    const s16x8* wbase = (const s16x8*)wf;

    f32x4 acc[4][4];                   // [tile T][o-block] (AGPRs)
#pragma unroll
    for (int T = 0; T < 4; ++T)
#pragma unroll
        for (int ob = 0; ob < 4; ++ob) acc[T][ob] = (f32x4){0, 0, 0, 0};

    uint2 G[3][8];                     // gather TRIPLE buffer (48 VGPR)
    s16x8 A[2][4];                     // weight double buffer (32 VGPR)

#define STAGE_G(S, KC)                                                    \
    {                                                                     \
        const uint4* fp = (const uint4*)&offF[(KC) * 32 + kg * 8];        \
        const uint4 fA = fp[0], fB = fp[1];                               \
        G[S][0] = *(const uint2*)(xpb + (pxoff + fA.x));                  \
        G[S][1] = *(const uint2*)(xpb + (pxoff + fA.y));                  \
        G[S][2] = *(const uint2*)(xpb + (pxoff + fA.z));                  \
        G[S][3] = *(const uint2*)(xpb + (pxoff + fA.w));                  \
        G[S][4] = *(const uint2*)(xpb + (pxoff + fB.x));                  \
        G[S][5] = *(const uint2*)(xpb + (pxoff + fB.y));                  \
        G[S][6] = *(const uint2*)(xpb + (pxoff + fB.z));                  \
        G[S][7] = *(const uint2*)(xpb + (pxoff + fB.w));                  \
    }

    // prologue: stage kc = 0, 1 (gathers) and kc = 0 (weights)
    STAGE_G(0, 0)
    STAGE_G(1, 1)
    {
        const s16x8* wp = wbase + lane;
        A[0][0] = wp[0]; A[0][1] = wp[64]; A[0][2] = wp[128]; A[0][3] = wp[192];
    }

#pragma unroll
    for (int kc = 0; kc < NKC; ++kc) {
        const int cur = kc % 3;
        const int pre = (kc + 2) % 3;
        if (kc + 2 < NKC) STAGE_G(pre, kc + 2)        // prefetch 2 ahead
        if (kc + 1 < NKC) {                           // weights 1 ahead
            const s16x8* wp = wbase + (((kc + 1) << 8) + lane);
            A[(kc + 1) & 1][0] = wp[0];   A[(kc + 1) & 1][1] = wp[64];
            A[(kc + 1) & 1][2] = wp[128]; A[(kc + 1) & 1][3] = wp[192];
        }
        __builtin_amdgcn_s_setprio(1);
#pragma unroll
        for (int T = 0; T < 4; ++T) {
            const u32 sel = (T & 1) ? 0x07060302u : 0x05040100u;
            const bool hi = (T >> 1) != 0;
            union { u32 u[4]; s16x8 v; } bu;
            bu.u[0] = __builtin_amdgcn_perm(hi ? G[cur][1].y : G[cur][1].x,
                                            hi ? G[cur][0].y : G[cur][0].x, sel);
            bu.u[1] = __builtin_amdgcn_perm(hi ? G[cur][3].y : G[cur][3].x,
                                            hi ? G[cur][2].y : G[cur][2].x, sel);
            bu.u[2] = __builtin_amdgcn_perm(hi ? G[cur][5].y : G[cur][5].x,
                                            hi ? G[cur][4].y : G[cur][4].x, sel);
            bu.u[3] = __builtin_amdgcn_perm(hi ? G[cur][7].y : G[cur][7].x,
                                            hi ? G[cur][6].y : G[cur][6].x, sel);

            acc[T][0] = __builtin_amdgcn_mfma_f32_16x16x32_bf16(A[kc & 1][0], bu.v, acc[T][0], 0, 0, 0);
            acc[T][1] = __builtin_amdgcn_mfma_f32_16x16x32_bf16(A[kc & 1][1], bu.v, acc[T][1], 0, 0, 0);
            acc[T][2] = __builtin_amdgcn_mfma_f32_16x16x32_bf16(A[kc & 1][2], bu.v, acc[T][2], 0, 0, 0);
            acc[T][3] = __builtin_amdgcn_mfma_f32_16x16x32_bf16(A[kc & 1][3], bu.v, acc[T][3], 0, 0, 0);
        }
        __builtin_amdgcn_s_setprio(0);
    }
#undef STAGE_G

    // D: col = lane&15 = pixel-group; row = kg*4 + r = o within 16-block.
    const int orow = kg << 2;
    const float4* bp = (const float4*)bias;
#pragma unroll
    for (int ob = 0; ob < 4; ++ob) {
        const float4 bb = bp[ob * 4 + kg];
        const float bv[4] = {bb.x, bb.y, bb.z, bb.w};
#pragma unroll
        for (int r = 0; r < 4; ++r) {
            const int o = ob * 16 + orow + r;
            f32x4 st;
            st[0] = acc[0][ob][r] + bv[r];
            st[1] = acc[1][ob][r] + bv[r];
            st[2] = acc[2][ob][r] + bv[r];
            st[3] = acc[3][ob][r] + bv[r];
            float* op = out + (((size_t)b * OC + o) * HH + h) * WW + wv * 64 + 4 * g16;
            __builtin_nontemporal_store(st, (f32x4*)op);
        }
    }
}

// ================= fallback (R1 fp32 path, tiny ws) ======================
__global__ void fovconv_transpose_w(const float* __restrict__ w,
                                    float* __restrict__ wT) {
    int i = blockIdx.x * 256 + threadIdx.x;
    const int N = OC * INC * KS * KS;
    if (i < N) {
        int o  = i / (INC * KS * KS);
        int ct = i % (INC * KS * KS);
        wT[ct * OC + o] = w[i];
    }
}

__global__ void __launch_bounds__(256)
fovconv_main(const float* __restrict__ x, const float* __restrict__ wT,
             const float* __restrict__ bias, float* __restrict__ out) {
    const int wpix = threadIdx.x;
    const int h    = blockIdx.x & (HH - 1);
    const int b    = blockIdx.x >> 8;
    float acc[OC];
#pragma unroll
    for (int o = 0; o < OC; ++o) acc[o] = 0.f;
    const float* xbp = x + (size_t)b * INC * HH * WW;
    for (int k = 0; k < KS; ++k) {
        const int dy = k - 5;
        for (int l = 0; l < KS; ++l) {
            const int dx = l - 5;
            const int d  = max(abs(dy), abs(dx));
            const int scale = (d <= 1) ? 1 : (d == 2 ? 3 : (d == 3 ? 5 : 7));
            const int sy = min(max(h + dy * scale, 0), HH - 1);
            const int sx = min(max(wpix + dx * scale, 0), WW - 1);
            const int base = sy * WW + sx;
            const int t = k * KS + l;
#pragma unroll
            for (int c = 0; c < INC; ++c) {
                const float xv = xbp[c * (HH * WW) + base];
                const float* wp = wT + (c * (KS * KS) + t) * OC;
#pragma unroll
                for (int o = 0; o < OC; ++o)
                    acc[o] = fmaf(xv, wp[o], acc[o]);
            }
        }
    }
    float* op = out + (((size_t)b * OC) * HH + h) * WW + wpix;
#pragma unroll
    for (int o = 0; o < OC; ++o)
        op[(size_t)o * HH * WW] = acc[o] + bias[o];
}

extern "C" void kernel_launch(void* const* d_in, const int* in_sizes, int n_in,
                              void* d_out, int out_size, void* d_ws, size_t ws_size,
                              hipStream_t stream) {
    const float* x    = (const float*)d_in[0];
    const float* wgt  = (const float*)d_in[1];
    const float* bias = (const float*)d_in[2];
    float* out = (float*)d_out;

    const size_t xs_bytes = (size_t)BB * NPAR * INC * PH * PW * 2;  // 16,023,552
    const size_t wf_bytes = (size_t)NKC * 4 * 64 * 8 * 2;           //     49,152

    if (ws_size >= xs_bytes + wf_bytes) {
        u16* xsb = (u16*)d_ws;
        u16* wf  = (u16*)((char*)d_ws + xs_bytes);
        prep_fused<<<96 + 978 * 8, 256, 0, stream>>>(x, wgt, xsb, wf);
        fov_mfma5<<<BB * HH, 256, 0, stream>>>(xsb, wf, bias, out);
    } else {
        float* wT = (float*)d_ws;
        const int NW = OC * INC * KS * KS;
        fovconv_transpose_w<<<(NW + 255) / 256, 256, 0, stream>>>(wgt, wT);
        fovconv_main<<<BB * HH, 256, 0, stream>>>(x, wT, bias, out);
    }
}

// Round 14
// 32.999 us; speedup vs baseline: 4.1108x; 1.1105x over previous
//
#include <hip/hip_runtime.h>

// FoveatedSamplingConv2d — bf16 MFMA implicit GEMM, 4-px-per-lane gathers,
// WEIGHTS SERVED FROM LDS (48KB staged once per block via global_load_lds;
// in-loop A-fragments via ds_read_b128 -> zero L1 pollution, gathers own L1),
// 2-stage gather pipeline, NT output stores, XCD-aligned prep.
// 4 shifted replicate-padded bf16 copies make every tap gather 8B-aligned.

#define HH 256
#define WW 256
#define INC 3
#define OC 64
#define KS 11
#define BB 4
#define NKC 12           // K chunks of 32 (3*128/32)
#define PH 326           // 256 + 2*35
#define PW 512           // padded row stride
#define PAD 35
#define NPAR 4           // shifted copies
#define HALFR 163        // PH/2 rows per XCD half

typedef __attribute__((ext_vector_type(4))) float f32x4;
typedef __attribute__((ext_vector_type(8))) short s16x8;
typedef unsigned int u32;
typedef unsigned short u16;

static __device__ __forceinline__ u16 f2bf(float f) {
    u32 u = __builtin_bit_cast(u32, f);
    u32 r = (u + 0x7FFFu + ((u >> 16) & 1u)) >> 16;   // RTNE (finite data)
    return (u16)r;
}

// ---- fused prep -----------------------------------------------------------
// blocks [0,96): W fragments. blocks [96,96+7824): pad copies, XCD-aligned:
//   target XCD k = pb&7 = 2*b + (py>=163) — matches main's reader mapping.
__global__ void __launch_bounds__(256)
prep_fused(const float* __restrict__ x, const float* __restrict__ w,
           u16* __restrict__ xs, u16* __restrict__ wf) {
    const int tid = threadIdx.x;
    if (blockIdx.x < 96) {
        int i = blockIdx.x * 256 + tid;              // 0..24575
        int j    = i & 7;
        int lane = (i >> 3) & 63;
        int ot   = (i >> 9) & 3;
        int kc   = i >> 11;
        int o  = ot * 16 + (lane & 15);
        int k  = kc * 32 + ((lane >> 4) << 3) + j;
        int c  = k >> 7;
        int tt = k & 127;
        float val = 0.f;
        if (tt < 121) {
            int ky = tt / 11, kx = tt % 11;
            val = w[((o * INC + c) * KS + ky) * KS + kx];
        }
        wf[i] = f2bf(val);
    } else {
        const int pb = blockIdx.x - 96;              // 0..7823
        const int k  = pb & 7;                       // target XCD
        const int i  = pb >> 3;                      // 0..977
        const int r  = i * 2 + (tid >> 7);           // 0..1955
        const int zl = r / HALFR;                    // 0..11  (par,c) plane
        const int pz = r - zl * HALFR;               // 0..162
        const int b    = k >> 1;
        const int py   = (k & 1) * HALFR + pz;       // 0..325
        const int c    = zl % INC;
        const int par  = zl / INC;                   // 0..3
        const int z    = (b * NPAR + par) * INC + c;
        const int px0  = (tid & 127) * 4;
        const int sy   = min(max(py - PAD, 0), HH - 1);
        const float* src = x + (((size_t)b * INC + c) * HH + sy) * WW;
        ushort4 o4;
        int s0 = min(max(px0 + 0 - PAD + par, 0), WW - 1);
        int s1 = min(max(px0 + 1 - PAD + par, 0), WW - 1);
        int s2 = min(max(px0 + 2 - PAD + par, 0), WW - 1);
        int s3 = min(max(px0 + 3 - PAD + par, 0), WW - 1);
        o4.x = f2bf(src[s0]); o4.y = f2bf(src[s1]);
        o4.z = f2bf(src[s2]); o4.w = f2bf(src[s3]);
        *(ushort4*)&xs[((size_t)z * PH + py) * PW + px0] = o4;
    }
}

// ---- main: 4 waves; wave = 64 px (4 MFMA tiles); weights from LDS --------
__global__ void __launch_bounds__(256, 3)
fov_mfma5(const u16* __restrict__ xs, const u16* __restrict__ wf,
          const float* __restrict__ bias, float* __restrict__ out) {
    __shared__ __align__(16) u32 swf[NKC * 1024];    // 49152 B weight frags
    __shared__ u32 offF[NKC * 32];                   //  1536 B tap offsets

    const int tid  = threadIdx.x;
    const int lane = tid & 63;
    const int wv   = tid >> 6;

    // per-tap global byte offsets into xs
    for (int t = tid; t < NKC * 32; t += 256) {
        int c = t >> 7, tt = t & 127;
        int dy = 0, dx = 0;
        if (tt < 121) {
            int ky = tt / 11, kx = tt - (tt / 11) * 11;
            int ay = ky - 5, ax = kx - 5;
            int d = max(abs(ay), abs(ax));
            int sc = (d <= 1) ? 1 : (d == 2 ? 3 : (d == 3 ? 5 : 7));
            dy = ay * sc; dx = ax * sc;
        }
        int par = (PAD + dx) & 3;
        offF[t] = (u32)(((((par * INC + c) * PH) + (PAD + dy)) * PW
                         + (PAD + dx - par)) * 2);
    }

    // stage the 48KB weight-fragment table into LDS (12 x 16B per thread)
    {
        const char* wsrc = (const char*)wf;
#pragma unroll
        for (int j = 0; j < NKC; ++j) {
            const int chunkbase = j * 256 + wv * 64;     // 16B chunks
            __builtin_amdgcn_global_load_lds(
                (const __attribute__((address_space(1))) void*)
                    (wsrc + ((size_t)(chunkbase + lane) << 4)),
                (__attribute__((address_space(3))) void*)
                    ((char*)swf + ((size_t)chunkbase << 4)),
                16, 0, 0);
        }
    }
    __syncthreads();   // drains vmcnt: swf + offF visible

    // bijective XCD swizzle: XCD = bid&7 = 2*b + (h>=128)
    const int obid = (blockIdx.x & 7) * 128 + (blockIdx.x >> 3);
    const int b = obid >> 8;
    const int h = obid & 255;
    const int g16 = lane & 15;         // pixel group: px = wv*64 + 4*g16 + T
    const int kg  = lane >> 4;         // tap group within chunk

    const char* xpb = (const char*)(xs + (size_t)b * (NPAR * INC * PH * PW));
    const u32 pxoff = (u32)((h * PW + wv * 64 + 4 * g16) * 2);
    const s16x8* wlds = (const s16x8*)swf;

    f32x4 acc[4][4];                   // [tile T][o-block] (AGPRs)
#pragma unroll
    for (int T = 0; T < 4; ++T)
#pragma unroll
        for (int ob = 0; ob < 4; ++ob) acc[T][ob] = (f32x4){0, 0, 0, 0};

    uint2 G[2][8];                     // gather double-buffer

#define STAGE_G(S, KC)                                                    \
    {                                                                     \
        const uint4* fp = (const uint4*)&offF[(KC) * 32 + kg * 8];        \
        const uint4 fA = fp[0], fB = fp[1];                               \
        G[S][0] = *(const uint2*)(xpb + (pxoff + fA.x));                  \
        G[S][1] = *(const uint2*)(xpb + (pxoff + fA.y));                  \
        G[S][2] = *(const uint2*)(xpb + (pxoff + fA.z));                  \
        G[S][3] = *(const uint2*)(xpb + (pxoff + fA.w));                  \
        G[S][4] = *(const uint2*)(xpb + (pxoff + fB.x));                  \
        G[S][5] = *(const uint2*)(xpb + (pxoff + fB.y));                  \
        G[S][6] = *(const uint2*)(xpb + (pxoff + fB.z));                  \
        G[S][7] = *(const uint2*)(xpb + (pxoff + fB.w));                  \
    }

    STAGE_G(0, 0)                      // prologue

#pragma unroll
    for (int kc = 0; kc < NKC; ++kc) {
        const int cur = kc & 1;
        if (kc + 1 < NKC) STAGE_G(cur ^ 1, kc + 1)   // prefetch next gathers

        // A-fragments from LDS (ds_read_b128, no L1 traffic)
        const s16x8 a0 = wlds[(kc << 8) + lane];
        const s16x8 a1 = wlds[(kc << 8) + 64 + lane];
        const s16x8 a2 = wlds[(kc << 8) + 128 + lane];
        const s16x8 a3 = wlds[(kc << 8) + 192 + lane];

        __builtin_amdgcn_s_setprio(1);
#pragma unroll
        for (int T = 0; T < 4; ++T) {
            const u32 sel = (T & 1) ? 0x07060302u : 0x05040100u;
            const bool hi = (T >> 1) != 0;
            union { u32 u[4]; s16x8 v; } bu;
            bu.u[0] = __builtin_amdgcn_perm(hi ? G[cur][1].y : G[cur][1].x,
                                            hi ? G[cur][0].y : G[cur][0].x, sel);
            bu.u[1] = __builtin_amdgcn_perm(hi ? G[cur][3].y : G[cur][3].x,
                                            hi ? G[cur][2].y : G[cur][2].x, sel);
            bu.u[2] = __builtin_amdgcn_perm(hi ? G[cur][5].y : G[cur][5].x,
                                            hi ? G[cur][4].y : G[cur][4].x, sel);
            bu.u[3] = __builtin_amdgcn_perm(hi ? G[cur][7].y : G[cur][7].x,
                                            hi ? G[cur][6].y : G[cur][6].x, sel);

            acc[T][0] = __builtin_amdgcn_mfma_f32_16x16x32_bf16(a0, bu.v, acc[T][0], 0, 0, 0);
            acc[T][1] = __builtin_amdgcn_mfma_f32_16x16x32_bf16(a1, bu.v, acc[T][1], 0, 0, 0);
            acc[T][2] = __builtin_amdgcn_mfma_f32_16x16x32_bf16(a2, bu.v, acc[T][2], 0, 0, 0);
            acc[T][3] = __builtin_amdgcn_mfma_f32_16x16x32_bf16(a3, bu.v, acc[T][3], 0, 0, 0);
        }
        __builtin_amdgcn_s_setprio(0);
    }
#undef STAGE_G

    // D: col = lane&15 = pixel-group; row = kg*4 + r = o within 16-block.
    const int orow = kg << 2;
    const float4* bp = (const float4*)bias;
#pragma unroll
    for (int ob = 0; ob < 4; ++ob) {
        const float4 bb = bp[ob * 4 + kg];
        const float bv[4] = {bb.x, bb.y, bb.z, bb.w};
#pragma unroll
        for (int r = 0; r < 4; ++r) {
            const int o = ob * 16 + orow + r;
            f32x4 st;
            st[0] = acc[0][ob][r] + bv[r];
            st[1] = acc[1][ob][r] + bv[r];
            st[2] = acc[2][ob][r] + bv[r];
            st[3] = acc[3][ob][r] + bv[r];
            float* op = out + (((size_t)b * OC + o) * HH + h) * WW + wv * 64 + 4 * g16;
            __builtin_nontemporal_store(st, (f32x4*)op);
        }
    }
}

// ================= fallback (R1 fp32 path, tiny ws) ======================
__global__ void fovconv_transpose_w(const float* __restrict__ w,
                                    float* __restrict__ wT) {
    int i = blockIdx.x * 256 + threadIdx.x;
    const int N = OC * INC * KS * KS;
    if (i < N) {
        int o  = i / (INC * KS * KS);
        int ct = i % (INC * KS * KS);
        wT[ct * OC + o] = w[i];
    }
}

__global__ void __launch_bounds__(256)
fovconv_main(const float* __restrict__ x, const float* __restrict__ wT,
             const float* __restrict__ bias, float* __restrict__ out) {
    const int wpix = threadIdx.x;
    const int h    = blockIdx.x & (HH - 1);
    const int b    = blockIdx.x >> 8;
    float acc[OC];
#pragma unroll
    for (int o = 0; o < OC; ++o) acc[o] = 0.f;
    const float* xbp = x + (size_t)b * INC * HH * WW;
    for (int k = 0; k < KS; ++k) {
        const int dy = k - 5;
        for (int l = 0; l < KS; ++l) {
            const int dx = l - 5;
            const int d  = max(abs(dy), abs(dx));
            const int scale = (d <= 1) ? 1 : (d == 2 ? 3 : (d == 3 ? 5 : 7));
            const int sy = min(max(h + dy * scale, 0), HH - 1);
            const int sx = min(max(wpix + dx * scale, 0), WW - 1);
            const int base = sy * WW + sx;
            const int t = k * KS + l;
#pragma unroll
            for (int c = 0; c < INC; ++c) {
                const float xv = xbp[c * (HH * WW) + base];
                const float* wp = wT + (c * (KS * KS) + t) * OC;
#pragma unroll
                for (int o = 0; o < OC; ++o)
                    acc[o] = fmaf(xv, wp[o], acc[o]);
            }
        }
    }
    float* op = out + (((size_t)b * OC) * HH + h) * WW + wpix;
#pragma unroll
    for (int o = 0; o < OC; ++o)
        op[(size_t)o * HH * WW] = acc[o] + bias[o];
}

extern "C" void kernel_launch(void* const* d_in, const int* in_sizes, int n_in,
                              void* d_out, int out_size, void* d_ws, size_t ws_size,
                              hipStream_t stream) {
    const float* x    = (const float*)d_in[0];
    const float* wgt  = (const float*)d_in[1];
    const float* bias = (const float*)d_in[2];
    float* out = (float*)d_out;

    const size_t xs_bytes = (size_t)BB * NPAR * INC * PH * PW * 2;  // 16,023,552
    const size_t wf_bytes = (size_t)NKC * 4 * 64 * 8 * 2;           //     49,152

    if (ws_size >= xs_bytes + wf_bytes) {
        u16* xsb = (u16*)d_ws;
        u16* wf  = (u16*)((char*)d_ws + xs_bytes);
        prep_fused<<<96 + 978 * 8, 256, 0, stream>>>(x, wgt, xsb, wf);
        fov_mfma5<<<BB * HH, 256, 0, stream>>>(xsb, wf, bias, out);
    } else {
        float* wT = (float*)d_ws;
        const int NW = OC * INC * KS * KS;
        fovconv_transpose_w<<<(NW + 255) / 256, 256, 0, stream>>>(wgt, wT);
        fovconv_main<<<BB * HH, 256, 0, stream>>>(x, wT, bias, out);
    }
}